// Round 4
// baseline (329.175 us; speedup 1.0000x reference)
//
#include <hip/hip_runtime.h>

#define D 128
#define G_GRAPHS 512
#define CCHUNK 16
#define NSLICE 16
#define BINMAX 6272

typedef _Float16 f16;
typedef _Float16 f16x2 __attribute__((ext_vector_type(2)));
typedef _Float16 f16x4 __attribute__((ext_vector_type(4)));
typedef _Float16 f16x8 __attribute__((ext_vector_type(8)));
typedef float f32x4 __attribute__((ext_vector_type(4)));

#define SCAN_CHUNK 2048   // 256 threads x 8 elems

// ---------------------------------------------------------------- per-(slice,chunk) histograms, LDS atomics only
// grid = 2*CCHUNK*NSLICE blocks: bit0=role (0:src->pho, 1:dst->phi), bits1-4=chunk, bits5+=slice
__global__ __launch_bounds__(256) void hist_kernel(const int* __restrict__ src, const int* __restrict__ dst,
                                                   int* __restrict__ pho, int* __restrict__ phi,
                                                   int E, int N, int slice_len, int binsz) {
    __shared__ int h[BINMAX];
    int id = blockIdx.x;
    int role = id & 1;
    int c = (id >> 1) & (CCHUNK - 1);
    int s = id >> 5;
    int c0 = c * binsz;
    int lim = min(binsz, N - c0);
    for (int i = threadIdx.x; i < lim; i += 256) h[i] = 0;
    __syncthreads();
    const int* arr = role ? dst : src;
    int e1 = min(E, (s + 1) * slice_len);
    for (int e = s * slice_len + (int)threadIdx.x; e < e1; e += 256) {
        unsigned v = (unsigned)(arr[e] - c0);
        if (v < (unsigned)lim) atomicAdd(&h[v], 1);
    }
    __syncthreads();
    int* outp = (role ? phi : pho) + s * N + c0;
    for (int i = threadIdx.x; i < lim; i += 256) outp[i] = h[i];
}

// ---------------------------------------------------------------- merge partials -> norms; phi -> slice-exclusive prefix
__global__ void merge_norm_kernel(const int* __restrict__ pho, int* __restrict__ phi,
                                  float* __restrict__ norm_src, float* __restrict__ norm_dst,
                                  int* __restrict__ deg_in_total, int N) {
    int n = blockIdx.x * 256 + threadIdx.x;
    if (n >= N) return;
    int so = 0;
    #pragma unroll
    for (int s = 0; s < NSLICE; ++s) so += pho[s * N + n];
    norm_src[n] = rsqrtf(fmaxf((float)so, 1.0f));
    int run = 0;
    #pragma unroll
    for (int s = 0; s < NSLICE; ++s) {
        int v = phi[s * N + n];
        phi[s * N + n] = run;      // exclusive prefix over slices within node bucket
        run += v;
    }
    deg_in_total[n] = run;
    norm_dst[n] = rsqrtf(fmaxf((float)run, 1.0f));
}

// ---------------------------------------------------------------- prescale: Xn = f16(feat * norm_src[row])
__global__ void prescale_kernel(const float* __restrict__ feat, const float* __restrict__ ns,
                                f16x4* __restrict__ out, int count /* N*32 */) {
    int i = blockIdx.x * 256 + threadIdx.x;
    if (i >= count) return;
    float4 v = ((const float4*)feat)[i];
    float s = ns[i >> 5];
    f16x4 o = { (f16)(v.x * s), (f16)(v.y * s), (f16)(v.z * s), (f16)(v.w * s) };
    out[i] = o;
}

// ---------------------------------------------------------------- hierarchical scan
__global__ __launch_bounds__(256) void scan1_kernel(const int* __restrict__ deg,
                                                    int* __restrict__ partial,
                                                    int* __restrict__ blocksums, int n) {
    __shared__ int wsum[4];
    int lane = threadIdx.x & 63, wid = threadIdx.x >> 6;
    int base = blockIdx.x * SCAN_CHUNK + (int)threadIdx.x * 8;
    int v[8]; int tsum = 0;
    #pragma unroll
    for (int i = 0; i < 8; ++i) { v[i] = (base + i < n) ? deg[base + i] : 0; tsum += v[i]; }
    int s = tsum;
    #pragma unroll
    for (int off = 1; off < 64; off <<= 1) {
        int t = __shfl_up(s, off);
        if (lane >= off) s += t;
    }
    if (lane == 63) wsum[wid] = s;
    __syncthreads();
    int woff = 0;
    for (int w = 0; w < wid; ++w) woff += wsum[w];
    int run = woff + s - tsum;
    #pragma unroll
    for (int i = 0; i < 8; ++i) {
        if (base + i < n) partial[base + i] = run;
        run += v[i];
    }
    if (threadIdx.x == 255) blocksums[blockIdx.x] = woff + s;
}

__global__ void scan2_kernel(int* __restrict__ bs, int* __restrict__ total_out, int nb) {
    int lane = threadIdx.x;  // 64 threads, 1 wave
    int carry = 0;
    for (int base = 0; base < nb; base += 64) {
        int i = base + lane;
        int v = (i < nb) ? bs[i] : 0;
        int s = v;
        #pragma unroll
        for (int off = 1; off < 64; off <<= 1) {
            int t = __shfl_up(s, off);
            if (lane >= off) s += t;
        }
        if (i < nb) bs[i] = carry + s - v;
        carry += __shfl(s, 63);
    }
    if (lane == 0) *total_out = carry;
}

__global__ void scan3_kernel(int* __restrict__ offsets, const int* __restrict__ bs, int n) {
    int i = blockIdx.x * 256 + threadIdx.x;
    if (i >= n) return;
    offsets[i] += bs[i >> 11];   // SCAN_CHUNK = 2048
}

// ---------------------------------------------------------------- CSR fill: LDS cursors, no global atomics
// grid = CCHUNK*NSLICE: bits0-3=chunk, bits4+=slice
__global__ __launch_bounds__(256) void fill_kernel(const int* __restrict__ src, const int* __restrict__ dst,
                                                   const int* __restrict__ offsets, const int* __restrict__ phi,
                                                   int* __restrict__ csr_src,
                                                   int E, int N, int slice_len, int binsz) {
    __shared__ int cur[BINMAX];
    int id = blockIdx.x;
    int c = id & (CCHUNK - 1);
    int s = id >> 4;
    int c0 = c * binsz;
    int lim = min(binsz, N - c0);
    for (int i = threadIdx.x; i < lim; i += 256)
        cur[i] = offsets[c0 + i] + phi[s * N + c0 + i];
    __syncthreads();
    int e1 = min(E, (s + 1) * slice_len);
    for (int e = s * slice_len + (int)threadIdx.x; e < e1; e += 256) {
        unsigned v = (unsigned)(dst[e] - c0);
        int sv = src[e];
        if (v < (unsigned)lim) {
            int p = atomicAdd(&cur[v], 1);
            csr_src[p] = sv;
        }
    }
}

// ---------------------------------------------------------------- gather: A[n] = f16(norm_dst[n] * sum_{s in in(n)} x[s])
// x pre-scaled by norm_src. 1 wave per node, 64 lanes x f16x2 (256B rows).
__global__ __launch_bounds__(256) void gather_kernel(const f16* __restrict__ x,
                                                     const float* __restrict__ norm_dst,
                                                     const int* __restrict__ offsets,
                                                     const int* __restrict__ csr_src,
                                                     f16* __restrict__ A, int N) {
    int node = __builtin_amdgcn_readfirstlane(blockIdx.x * 4 + ((int)threadIdx.x >> 6));
    int lane = threadIdx.x & 63;
    if (node >= N) return;
    int beg = offsets[node], end = offsets[node + 1];
    const f16x2* x2 = (const f16x2*)x;
    float ax[8] = {0.f}, ay[8] = {0.f};
    int e = beg;
    for (; e + 8 <= end; e += 8) {
        int s[8];
        #pragma unroll
        for (int i = 0; i < 8; ++i) s[i] = csr_src[e + i];
        f16x2 v[8];
        #pragma unroll
        for (int i = 0; i < 8; ++i) v[i] = x2[s[i] * 64 + lane];
        #pragma unroll
        for (int i = 0; i < 8; ++i) { ax[i] += (float)v[i].x; ay[i] += (float)v[i].y; }
    }
    for (; e + 2 <= end; e += 2) {
        int s0 = csr_src[e], s1 = csr_src[e + 1];
        f16x2 v0 = x2[s0 * 64 + lane], v1 = x2[s1 * 64 + lane];
        ax[0] += (float)v0.x; ay[0] += (float)v0.y;
        ax[1] += (float)v1.x; ay[1] += (float)v1.y;
    }
    if (e < end) {
        int s0 = csr_src[e];
        f16x2 v0 = x2[s0 * 64 + lane];
        ax[2] += (float)v0.x; ay[2] += (float)v0.y;
    }
    float nd = norm_dst[node];
    float ox = (((ax[0] + ax[1]) + (ax[2] + ax[3])) + ((ax[4] + ax[5]) + (ax[6] + ax[7]))) * nd;
    float oy = (((ay[0] + ay[1]) + (ay[2] + ay[3])) + ((ay[4] + ay[5]) + (ay[6] + ay[7]))) * nd;
    f16x2 o; o.x = (f16)ox; o.y = (f16)oy;
    ((f16x2*)A)[node * 64 + lane] = o;
}

// ---------------------------------------------------------------- GEMM: out = relu(A[M,128] @ W[128,128] + b) [* rowscale] [+ gate]
template <typename OutT, bool SCALE, bool GATE>
__global__ __launch_bounds__(256) void gemm_kernel(const f16* __restrict__ A,
                                                   const float* __restrict__ Wg,
                                                   const float* __restrict__ bias,
                                                   const float* __restrict__ rowscale,
                                                   const float* __restrict__ wgv,
                                                   const float* __restrict__ bgv,
                                                   float* __restrict__ gate_out,
                                                   OutT* __restrict__ out, int M) {
    __shared__ f16 Wf[4 * 8 * 64 * 8];   // 32 KiB
    for (int i = threadIdx.x; i < 2048; i += 256) {   // i = kg*128 + j
        int kg = i >> 7, j = i & 127;
        int k0 = kg * 8;
        f16x8 tmp;
        #pragma unroll
        for (int b = 0; b < 8; ++b) tmp[b] = (f16)Wg[(k0 + b) * D + j];
        int t = k0 >> 5, c = j >> 4;
        int l = ((k0 & 31) >> 3) * 16 + (j & 15);
        *(f16x8*)&Wf[((t * 8 + c) * 64 + l) * 8] = tmp;
    }
    __syncthreads();
    int wave = threadIdx.x >> 6, lane = threadIdx.x & 63;

    for (int row0 = (blockIdx.x * 4 + wave) * 16; row0 < M; row0 += gridDim.x * 64) {
        int arow = row0 + (lane & 15);
        const f16* Abase = A + arow * D + (lane >> 4) * 8;
        f16x8 a[4];
        #pragma unroll
        for (int t = 0; t < 4; ++t) a[t] = *(const f16x8*)(Abase + t * 32);

        float ns[4];
        if (SCALE) {
            #pragma unroll
            for (int r = 0; r < 4; ++r) ns[r] = rowscale[row0 + (lane >> 4) * 4 + r];
        }
        float dotr[4] = {0.f, 0.f, 0.f, 0.f};

        #pragma unroll
        for (int c = 0; c < 8; ++c) {
            f32x4 acc = {0.f, 0.f, 0.f, 0.f};
            #pragma unroll
            for (int t = 0; t < 4; ++t) {
                f16x8 bf = *(const f16x8*)&Wf[((t * 8 + c) * 64 + lane) * 8];
                acc = __builtin_amdgcn_mfma_f32_16x16x32_f16(a[t], bf, acc, 0, 0, 0);
            }
            int col = c * 16 + (lane & 15);
            float bj = bias[col];
            float wgc = GATE ? wgv[col] : 0.f;
            #pragma unroll
            for (int r = 0; r < 4; ++r) {
                int row = row0 + (lane >> 4) * 4 + r;
                float v = fmaxf(acc[r] + bj, 0.f);
                if (SCALE) v *= ns[r];
                out[row * D + col] = (OutT)v;
                if (GATE) dotr[r] += v * wgc;
            }
        }
        if (GATE) {
            float bg0 = bgv[0];
            #pragma unroll
            for (int r = 0; r < 4; ++r) {
                float d = dotr[r];
                d += __shfl_xor(d, 1); d += __shfl_xor(d, 2);
                d += __shfl_xor(d, 4); d += __shfl_xor(d, 8);
                if ((lane & 15) == 0)
                    gate_out[row0 + (lane >> 4) * 4 + r] = 1.0f / (1.0f + __expf(-(d + bg0)));
            }
        }
    }
}

// ---------------------------------------------------------------- graph ranges (graph_ids sorted)
__global__ void gstart_kernel(const int* __restrict__ gid, int* __restrict__ gstart, int N, int G) {
    int n = blockIdx.x * 256 + threadIdx.x;
    if (n >= N) return;
    int g = gid[n];
    if (n == 0) {
        for (int x = 0; x <= g; ++x) gstart[x] = 0;
    } else {
        int pg = gid[n - 1];
        for (int x = pg + 1; x <= g; ++x) gstart[x] = n;
    }
    if (n == N - 1) {
        for (int x = g + 1; x <= G; ++x) gstart[x] = N;
    }
}

// ---------------------------------------------------------------- wh[g] = sum_{n in graph g} gate[n]*h[n]
__global__ __launch_bounds__(256) void gagg_kernel(const float* __restrict__ h,
                                                   const float* __restrict__ gate,
                                                   const int* __restrict__ gstart,
                                                   float* __restrict__ wh) {
    __shared__ float part[4][D];
    int g = blockIdx.x;
    int wave = threadIdx.x >> 6, lane = threadIdx.x & 63;
    int beg = gstart[g], end = gstart[g + 1];
    float2 acc = {0.f, 0.f};
    for (int n = beg + wave; n < end; n += 4) {
        float gv = gate[n];
        float2 hv = ((const float2*)(h + n * D))[lane];
        acc.x += gv * hv.x;
        acc.y += gv * hv.y;
    }
    part[wave][lane * 2]     = acc.x;
    part[wave][lane * 2 + 1] = acc.y;
    __syncthreads();
    if (wave == 0) {
        float sx = 0.f, sy = 0.f;
        #pragma unroll
        for (int w = 0; w < 4; ++w) { sx += part[w][lane * 2]; sy += part[w][lane * 2 + 1]; }
        float2 o = {sx, sy};
        ((float2*)(wh + g * D))[lane] = o;
    }
}

// ---------------------------------------------------------------- launch
extern "C" void kernel_launch(void* const* d_in, const int* in_sizes, int n_in,
                              void* d_out, int out_size, void* d_ws, size_t ws_size,
                              hipStream_t stream) {
    const int*   src  = (const int*)d_in[0];
    const int*   dst  = (const int*)d_in[1];
    const int*   gid  = (const int*)d_in[2];
    const float* feat = (const float*)d_in[3];
    const float* w1   = (const float*)d_in[4];
    const float* b1   = (const float*)d_in[5];
    const float* w2   = (const float*)d_in[6];
    const float* b2   = (const float*)d_in[7];
    const float* wg   = (const float*)d_in[8];
    const float* bg   = (const float*)d_in[9];
    int E = in_sizes[0];
    int N = in_sizes[2];
    const int G = G_GRAPHS;

    int binsz     = (N + CCHUNK - 1) / CCHUNK;     // 6250 for N=100000 (must be <= BINMAX)
    int slice_len = (E + NSLICE - 1) / NSLICE;     // 50000 for E=800000

    char* ws = (char*)d_ws;
    size_t off = 0;
    auto carve = [&](size_t bytes) { void* p = ws + off; off = (off + bytes + 255) & ~(size_t)255; return p; };
    int*   pho       = (int*)  carve((size_t)NSLICE * N * 4);
    int*   phi       = (int*)  carve((size_t)NSLICE * N * 4);   // becomes slice-exclusive prefix
    float* norm_src  = (float*)carve((size_t)N * 4);
    float* norm_dst  = (float*)carve((size_t)N * 4);
    int*   deg_in_t  = (int*)  carve((size_t)N * 4);
    int*   offsets   = (int*)  carve((size_t)(N + 1) * 4);
    int*   blocksums = (int*)  carve((size_t)64 * 4);
    int*   csr_src   = (int*)  carve((size_t)E * 4);
    f16*   Xh        = (f16*)  carve((size_t)N * D * 2);  // Xn for layer1, then h1*norm_src
    f16*   A         = (f16*)  carve((size_t)N * D * 2);
    float* gate      = (float*)carve((size_t)N * 4);
    int*   gstart    = (int*)  carve((size_t)(G + 1) * 4);

    float* wh_out = (float*)d_out;                  // [512, 128]
    float* h_out  = (float*)d_out + (size_t)G * D;  // [N, 128]

    int nb = (N + SCAN_CHUNK - 1) / SCAN_CHUNK;     // 49 blocks for N=100000

    hist_kernel<<<2 * CCHUNK * NSLICE, 256, 0, stream>>>(src, dst, pho, phi, E, N, slice_len, binsz);
    merge_norm_kernel<<<(N + 255) / 256, 256, 0, stream>>>(pho, phi, norm_src, norm_dst, deg_in_t, N);
    prescale_kernel<<<(N * 32 + 255) / 256, 256, 0, stream>>>(feat, norm_src, (f16x4*)Xh, N * 32);

    scan1_kernel<<<nb, 256, 0, stream>>>(deg_in_t, offsets, blocksums, N);
    scan2_kernel<<<1, 64, 0, stream>>>(blocksums, offsets + N, nb);
    scan3_kernel<<<(N + 255) / 256, 256, 0, stream>>>(offsets, blocksums, N);
    fill_kernel<<<CCHUNK * NSLICE, 256, 0, stream>>>(src, dst, offsets, phi, csr_src, E, N, slice_len, binsz);

    // layer 1
    gather_kernel<<<(N + 3) / 4, 256, 0, stream>>>(Xh, norm_dst, offsets, csr_src, A, N);
    gemm_kernel<f16, true, false><<<512, 256, 0, stream>>>(A, w1, b1, norm_src, nullptr, nullptr, nullptr, Xh, N);
    // layer 2
    gather_kernel<<<(N + 3) / 4, 256, 0, stream>>>(Xh, norm_dst, offsets, csr_src, A, N);
    gemm_kernel<float, false, true><<<512, 256, 0, stream>>>(A, w2, b2, nullptr, wg, bg, gate, h_out, N);

    gstart_kernel<<<(N + 255) / 256, 256, 0, stream>>>(gid, gstart, N, G);
    gagg_kernel<<<G, 256, 0, stream>>>(h_out, gate, gstart, wh_out);
}

// Round 5
// 243.997 us; speedup vs baseline: 1.3491x; 1.3491x over previous
//
#include <hip/hip_runtime.h>

#define D 128
#define G_GRAPHS 512
#define CCHUNK 16
#define NSLICE 64
#define BINMAX 6272

typedef _Float16 f16;
typedef _Float16 f16x2 __attribute__((ext_vector_type(2)));
typedef _Float16 f16x4 __attribute__((ext_vector_type(4)));
typedef _Float16 f16x8 __attribute__((ext_vector_type(8)));
typedef float f32x4 __attribute__((ext_vector_type(4)));
typedef unsigned short u16;

#define SCAN_CHUNK 2048   // 256 threads x 8 elems

// ---------------------------------------------------------------- per-(slice,chunk) histograms, LDS atomics only
// grid = 2*CCHUNK*NSLICE blocks: bit0=role (0:src->pho, 1:dst->phi), bits1-4=chunk, bits5+=slice
__global__ __launch_bounds__(256) void hist_kernel(const int* __restrict__ src, const int* __restrict__ dst,
                                                   u16* __restrict__ pho, u16* __restrict__ phi,
                                                   int E, int N, int slice_len, int binsz) {
    __shared__ int h[BINMAX];
    int id = blockIdx.x;
    int role = id & 1;
    int c = (id >> 1) & (CCHUNK - 1);
    int s = id >> 5;
    int c0 = c * binsz;
    int lim = min(binsz, N - c0);
    for (int i = threadIdx.x; i < lim; i += 256) h[i] = 0;
    __syncthreads();
    const int* arr = role ? dst : src;
    int e1 = min(E, (s + 1) * slice_len);
    for (int e = s * slice_len + (int)threadIdx.x; e < e1; e += 256) {
        unsigned v = (unsigned)(arr[e] - c0);
        if (v < (unsigned)lim) atomicAdd(&h[v], 1);
    }
    __syncthreads();
    u16* outp = (role ? phi : pho) + (size_t)s * N + c0;
    for (int i = threadIdx.x; i < lim; i += 256) outp[i] = (u16)h[i];
}

// ---------------------------------------------------------------- merge partials -> norms; phi -> slice-exclusive prefix
__global__ void merge_norm_kernel(const u16* __restrict__ pho, u16* __restrict__ phi,
                                  float* __restrict__ norm_src, float* __restrict__ norm_dst,
                                  int* __restrict__ deg_in_total, int N) {
    int n = blockIdx.x * 256 + threadIdx.x;
    if (n >= N) return;
    int so = 0;
    #pragma unroll 8
    for (int s = 0; s < NSLICE; ++s) so += pho[(size_t)s * N + n];
    norm_src[n] = rsqrtf(fmaxf((float)so, 1.0f));
    int run = 0;
    #pragma unroll 8
    for (int s = 0; s < NSLICE; ++s) {
        int v = phi[(size_t)s * N + n];
        phi[(size_t)s * N + n] = (u16)run;   // exclusive prefix over slices within node bucket
        run += v;
    }
    deg_in_total[n] = run;
    norm_dst[n] = rsqrtf(fmaxf((float)run, 1.0f));
}

// ---------------------------------------------------------------- prescale: Xn = f16(feat * norm_src[row])
__global__ void prescale_kernel(const float* __restrict__ feat, const float* __restrict__ ns,
                                f16x4* __restrict__ out, int count /* N*32 */) {
    int i = blockIdx.x * 256 + threadIdx.x;
    if (i >= count) return;
    float4 v = ((const float4*)feat)[i];
    float s = ns[i >> 5];
    f16x4 o = { (f16)(v.x * s), (f16)(v.y * s), (f16)(v.z * s), (f16)(v.w * s) };
    out[i] = o;
}

// ---------------------------------------------------------------- hierarchical scan
__global__ __launch_bounds__(256) void scan1_kernel(const int* __restrict__ deg,
                                                    int* __restrict__ partial,
                                                    int* __restrict__ blocksums, int n) {
    __shared__ int wsum[4];
    int lane = threadIdx.x & 63, wid = threadIdx.x >> 6;
    int base = blockIdx.x * SCAN_CHUNK + (int)threadIdx.x * 8;
    int v[8]; int tsum = 0;
    #pragma unroll
    for (int i = 0; i < 8; ++i) { v[i] = (base + i < n) ? deg[base + i] : 0; tsum += v[i]; }
    int s = tsum;
    #pragma unroll
    for (int off = 1; off < 64; off <<= 1) {
        int t = __shfl_up(s, off);
        if (lane >= off) s += t;
    }
    if (lane == 63) wsum[wid] = s;
    __syncthreads();
    int woff = 0;
    for (int w = 0; w < wid; ++w) woff += wsum[w];
    int run = woff + s - tsum;
    #pragma unroll
    for (int i = 0; i < 8; ++i) {
        if (base + i < n) partial[base + i] = run;
        run += v[i];
    }
    if (threadIdx.x == 255) blocksums[blockIdx.x] = woff + s;
}

__global__ void scan2_kernel(int* __restrict__ bs, int* __restrict__ total_out, int nb) {
    int lane = threadIdx.x;  // 64 threads, 1 wave
    int carry = 0;
    for (int base = 0; base < nb; base += 64) {
        int i = base + lane;
        int v = (i < nb) ? bs[i] : 0;
        int s = v;
        #pragma unroll
        for (int off = 1; off < 64; off <<= 1) {
            int t = __shfl_up(s, off);
            if (lane >= off) s += t;
        }
        if (i < nb) bs[i] = carry + s - v;
        carry += __shfl(s, 63);
    }
    if (lane == 0) *total_out = carry;
}

__global__ void scan3_kernel(int* __restrict__ offsets, const int* __restrict__ bs, int n) {
    int i = blockIdx.x * 256 + threadIdx.x;
    if (i >= n) return;
    offsets[i] += bs[i >> 11];   // SCAN_CHUNK = 2048
}

// ---------------------------------------------------------------- CSR fill: LDS cursors, no global atomics
// grid = CCHUNK*NSLICE: bits0-3=chunk, bits4+=slice
__global__ __launch_bounds__(256) void fill_kernel(const int* __restrict__ src, const int* __restrict__ dst,
                                                   const int* __restrict__ offsets, const u16* __restrict__ phi,
                                                   int* __restrict__ csr_src,
                                                   int E, int N, int slice_len, int binsz) {
    __shared__ int cur[BINMAX];
    int id = blockIdx.x;
    int c = id & (CCHUNK - 1);
    int s = id >> 4;
    int c0 = c * binsz;
    int lim = min(binsz, N - c0);
    for (int i = threadIdx.x; i < lim; i += 256)
        cur[i] = offsets[c0 + i] + phi[(size_t)s * N + c0 + i];
    __syncthreads();
    int e1 = min(E, (s + 1) * slice_len);
    for (int e = s * slice_len + (int)threadIdx.x; e < e1; e += 256) {
        unsigned v = (unsigned)(dst[e] - c0);
        int sv = src[e];
        if (v < (unsigned)lim) {
            int p = atomicAdd(&cur[v], 1);
            csr_src[p] = sv;
        }
    }
}

// ---------------------------------------------------------------- gather: A[n] = f16(norm_dst[n] * sum_{s in in(n)} x[s])
// x pre-scaled by norm_src. 1 wave per node, 64 lanes x f16x2 (256B rows).
__global__ __launch_bounds__(256) void gather_kernel(const f16* __restrict__ x,
                                                     const float* __restrict__ norm_dst,
                                                     const int* __restrict__ offsets,
                                                     const int* __restrict__ csr_src,
                                                     f16* __restrict__ A, int N) {
    int node = __builtin_amdgcn_readfirstlane(blockIdx.x * 4 + ((int)threadIdx.x >> 6));
    int lane = threadIdx.x & 63;
    if (node >= N) return;
    int beg = offsets[node], end = offsets[node + 1];
    const f16x2* x2 = (const f16x2*)x;
    float ax[8] = {0.f}, ay[8] = {0.f};
    int e = beg;
    for (; e + 8 <= end; e += 8) {
        int s[8];
        #pragma unroll
        for (int i = 0; i < 8; ++i) s[i] = csr_src[e + i];
        f16x2 v[8];
        #pragma unroll
        for (int i = 0; i < 8; ++i) v[i] = x2[s[i] * 64 + lane];
        #pragma unroll
        for (int i = 0; i < 8; ++i) { ax[i] += (float)v[i].x; ay[i] += (float)v[i].y; }
    }
    for (; e + 2 <= end; e += 2) {
        int s0 = csr_src[e], s1 = csr_src[e + 1];
        f16x2 v0 = x2[s0 * 64 + lane], v1 = x2[s1 * 64 + lane];
        ax[0] += (float)v0.x; ay[0] += (float)v0.y;
        ax[1] += (float)v1.x; ay[1] += (float)v1.y;
    }
    if (e < end) {
        int s0 = csr_src[e];
        f16x2 v0 = x2[s0 * 64 + lane];
        ax[2] += (float)v0.x; ay[2] += (float)v0.y;
    }
    float nd = norm_dst[node];
    float ox = (((ax[0] + ax[1]) + (ax[2] + ax[3])) + ((ax[4] + ax[5]) + (ax[6] + ax[7]))) * nd;
    float oy = (((ay[0] + ay[1]) + (ay[2] + ay[3])) + ((ay[4] + ay[5]) + (ay[6] + ay[7]))) * nd;
    f16x2 o; o.x = (f16)ox; o.y = (f16)oy;
    ((f16x2*)A)[node * 64 + lane] = o;
}

// ---------------------------------------------------------------- GEMM: out = relu(A[M,128] @ W[128,128] + b) [* rowscale] [+ gate]
template <typename OutT, bool SCALE, bool GATE>
__global__ __launch_bounds__(256) void gemm_kernel(const f16* __restrict__ A,
                                                   const float* __restrict__ Wg,
                                                   const float* __restrict__ bias,
                                                   const float* __restrict__ rowscale,
                                                   const float* __restrict__ wgv,
                                                   const float* __restrict__ bgv,
                                                   float* __restrict__ gate_out,
                                                   OutT* __restrict__ out, int M) {
    __shared__ f16 Wf[4 * 8 * 64 * 8];   // 32 KiB
    for (int i = threadIdx.x; i < 2048; i += 256) {   // i = kg*128 + j
        int kg = i >> 7, j = i & 127;
        int k0 = kg * 8;
        f16x8 tmp;
        #pragma unroll
        for (int b = 0; b < 8; ++b) tmp[b] = (f16)Wg[(k0 + b) * D + j];
        int t = k0 >> 5, c = j >> 4;
        int l = ((k0 & 31) >> 3) * 16 + (j & 15);
        *(f16x8*)&Wf[((t * 8 + c) * 64 + l) * 8] = tmp;
    }
    __syncthreads();
    int wave = threadIdx.x >> 6, lane = threadIdx.x & 63;

    for (int row0 = (blockIdx.x * 4 + wave) * 16; row0 < M; row0 += gridDim.x * 64) {
        int arow = row0 + (lane & 15);
        const f16* Abase = A + arow * D + (lane >> 4) * 8;
        f16x8 a[4];
        #pragma unroll
        for (int t = 0; t < 4; ++t) a[t] = *(const f16x8*)(Abase + t * 32);

        float ns[4];
        if (SCALE) {
            #pragma unroll
            for (int r = 0; r < 4; ++r) ns[r] = rowscale[row0 + (lane >> 4) * 4 + r];
        }
        float dotr[4] = {0.f, 0.f, 0.f, 0.f};

        #pragma unroll
        for (int c = 0; c < 8; ++c) {
            f32x4 acc = {0.f, 0.f, 0.f, 0.f};
            #pragma unroll
            for (int t = 0; t < 4; ++t) {
                f16x8 bf = *(const f16x8*)&Wf[((t * 8 + c) * 64 + lane) * 8];
                acc = __builtin_amdgcn_mfma_f32_16x16x32_f16(a[t], bf, acc, 0, 0, 0);
            }
            int col = c * 16 + (lane & 15);
            float bj = bias[col];
            float wgc = GATE ? wgv[col] : 0.f;
            #pragma unroll
            for (int r = 0; r < 4; ++r) {
                int row = row0 + (lane >> 4) * 4 + r;
                float v = fmaxf(acc[r] + bj, 0.f);
                if (SCALE) v *= ns[r];
                out[row * D + col] = (OutT)v;
                if (GATE) dotr[r] += v * wgc;
            }
        }
        if (GATE) {
            float bg0 = bgv[0];
            #pragma unroll
            for (int r = 0; r < 4; ++r) {
                float d = dotr[r];
                d += __shfl_xor(d, 1); d += __shfl_xor(d, 2);
                d += __shfl_xor(d, 4); d += __shfl_xor(d, 8);
                if ((lane & 15) == 0)
                    gate_out[row0 + (lane >> 4) * 4 + r] = 1.0f / (1.0f + __expf(-(d + bg0)));
            }
        }
    }
}

// ---------------------------------------------------------------- graph ranges (graph_ids sorted)
__global__ void gstart_kernel(const int* __restrict__ gid, int* __restrict__ gstart, int N, int G) {
    int n = blockIdx.x * 256 + threadIdx.x;
    if (n >= N) return;
    int g = gid[n];
    if (n == 0) {
        for (int x = 0; x <= g; ++x) gstart[x] = 0;
    } else {
        int pg = gid[n - 1];
        for (int x = pg + 1; x <= g; ++x) gstart[x] = n;
    }
    if (n == N - 1) {
        for (int x = g + 1; x <= G; ++x) gstart[x] = N;
    }
}

// ---------------------------------------------------------------- wh[g] = sum_{n in graph g} gate[n]*h[n]
__global__ __launch_bounds__(256) void gagg_kernel(const float* __restrict__ h,
                                                   const float* __restrict__ gate,
                                                   const int* __restrict__ gstart,
                                                   float* __restrict__ wh) {
    __shared__ float part[4][D];
    int g = blockIdx.x;
    int wave = threadIdx.x >> 6, lane = threadIdx.x & 63;
    int beg = gstart[g], end = gstart[g + 1];
    float2 acc = {0.f, 0.f};
    for (int n = beg + wave; n < end; n += 4) {
        float gv = gate[n];
        float2 hv = ((const float2*)(h + n * D))[lane];
        acc.x += gv * hv.x;
        acc.y += gv * hv.y;
    }
    part[wave][lane * 2]     = acc.x;
    part[wave][lane * 2 + 1] = acc.y;
    __syncthreads();
    if (wave == 0) {
        float sx = 0.f, sy = 0.f;
        #pragma unroll
        for (int w = 0; w < 4; ++w) { sx += part[w][lane * 2]; sy += part[w][lane * 2 + 1]; }
        float2 o = {sx, sy};
        ((float2*)(wh + g * D))[lane] = o;
    }
}

// ---------------------------------------------------------------- launch
extern "C" void kernel_launch(void* const* d_in, const int* in_sizes, int n_in,
                              void* d_out, int out_size, void* d_ws, size_t ws_size,
                              hipStream_t stream) {
    const int*   src  = (const int*)d_in[0];
    const int*   dst  = (const int*)d_in[1];
    const int*   gid  = (const int*)d_in[2];
    const float* feat = (const float*)d_in[3];
    const float* w1   = (const float*)d_in[4];
    const float* b1   = (const float*)d_in[5];
    const float* w2   = (const float*)d_in[6];
    const float* b2   = (const float*)d_in[7];
    const float* wg   = (const float*)d_in[8];
    const float* bg   = (const float*)d_in[9];
    int E = in_sizes[0];
    int N = in_sizes[2];
    const int G = G_GRAPHS;

    int binsz     = (N + CCHUNK - 1) / CCHUNK;     // 6250 for N=100000 (must be <= BINMAX)
    int slice_len = (E + NSLICE - 1) / NSLICE;     // 12500 for E=800000

    char* ws = (char*)d_ws;
    size_t off = 0;
    auto carve = [&](size_t bytes) { void* p = ws + off; off = (off + bytes + 255) & ~(size_t)255; return p; };
    u16*   pho       = (u16*)  carve((size_t)NSLICE * N * 2);
    u16*   phi       = (u16*)  carve((size_t)NSLICE * N * 2);   // becomes slice-exclusive prefix
    float* norm_src  = (float*)carve((size_t)N * 4);
    float* norm_dst  = (float*)carve((size_t)N * 4);
    int*   deg_in_t  = (int*)  carve((size_t)N * 4);
    int*   offsets   = (int*)  carve((size_t)(N + 1) * 4);
    int*   blocksums = (int*)  carve((size_t)64 * 4);
    int*   csr_src   = (int*)  carve((size_t)E * 4);
    f16*   Xh        = (f16*)  carve((size_t)N * D * 2);  // Xn for layer1, then h1*norm_src
    f16*   A         = (f16*)  carve((size_t)N * D * 2);
    float* gate      = (float*)carve((size_t)N * 4);
    int*   gstart    = (int*)  carve((size_t)(G + 1) * 4);

    float* wh_out = (float*)d_out;                  // [512, 128]
    float* h_out  = (float*)d_out + (size_t)G * D;  // [N, 128]

    int nb = (N + SCAN_CHUNK - 1) / SCAN_CHUNK;     // 49 blocks for N=100000

    hist_kernel<<<2 * CCHUNK * NSLICE, 256, 0, stream>>>(src, dst, pho, phi, E, N, slice_len, binsz);
    merge_norm_kernel<<<(N + 255) / 256, 256, 0, stream>>>(pho, phi, norm_src, norm_dst, deg_in_t, N);
    prescale_kernel<<<(N * 32 + 255) / 256, 256, 0, stream>>>(feat, norm_src, (f16x4*)Xh, N * 32);

    scan1_kernel<<<nb, 256, 0, stream>>>(deg_in_t, offsets, blocksums, N);
    scan2_kernel<<<1, 64, 0, stream>>>(blocksums, offsets + N, nb);
    scan3_kernel<<<(N + 255) / 256, 256, 0, stream>>>(offsets, blocksums, N);
    fill_kernel<<<CCHUNK * NSLICE, 256, 0, stream>>>(src, dst, offsets, phi, csr_src, E, N, slice_len, binsz);

    // layer 1
    gather_kernel<<<(N + 3) / 4, 256, 0, stream>>>(Xh, norm_dst, offsets, csr_src, A, N);
    gemm_kernel<f16, true, false><<<512, 256, 0, stream>>>(A, w1, b1, norm_src, nullptr, nullptr, nullptr, Xh, N);
    // layer 2
    gather_kernel<<<(N + 3) / 4, 256, 0, stream>>>(Xh, norm_dst, offsets, csr_src, A, N);
    gemm_kernel<float, false, true><<<512, 256, 0, stream>>>(A, w2, b2, nullptr, wg, bg, gate, h_out, N);

    gstart_kernel<<<(N + 255) / 256, 256, 0, stream>>>(gid, gstart, N, G);
    gagg_kernel<<<G, 256, 0, stream>>>(h_out, gate, gstart, wh_out);
}

// Round 6
// 214.338 us; speedup vs baseline: 1.5358x; 1.1384x over previous
//
#include <hip/hip_runtime.h>

#define D 128
#define G_GRAPHS 512
#define CCHUNK 8
#define NSLICE 64
#define BINMAX 12544   // bins per chunk, packed 2-per-u32 -> 25088 B LDS

typedef _Float16 f16;
typedef _Float16 f16x2 __attribute__((ext_vector_type(2)));
typedef _Float16 f16x4 __attribute__((ext_vector_type(4)));
typedef _Float16 f16x8 __attribute__((ext_vector_type(8)));
typedef float f32x4 __attribute__((ext_vector_type(4)));
typedef unsigned short u16;

#define SCAN_CHUNK 2048   // 256 threads x 8 elems

// ---------------------------------------------------------------- per-(slice,chunk) histograms, packed u16 LDS bins
// grid = (CCHUNK, 2, NSLICE): x=chunk, y=role (0:src->pho, 1:dst->phi+rank), z=slice
__global__ __launch_bounds__(256) void hist_kernel(const int* __restrict__ src, const int* __restrict__ dst,
                                                   u16* __restrict__ pho, u16* __restrict__ phi,
                                                   u16* __restrict__ rank,
                                                   int E, int N, int slice_len, int binsz) {
    __shared__ unsigned hp[BINMAX / 2];
    int c = blockIdx.x, role = blockIdx.y, s = blockIdx.z;
    int c0 = c * binsz;
    int lim = min(binsz, N - c0);
    for (int i = threadIdx.x; i < ((lim + 1) >> 1); i += 256) hp[i] = 0;
    __syncthreads();
    const int* arr = role ? dst : src;
    int e1 = min(E, (s + 1) * slice_len);
    if (role) {
        for (int e = s * slice_len + (int)threadIdx.x; e < e1; e += 256) {
            unsigned v = (unsigned)(arr[e] - c0);
            if (v < (unsigned)lim) {
                unsigned add = (v & 1) ? 0x10000u : 1u;
                unsigned old = atomicAdd(&hp[v >> 1], add);
                rank[e] = (u16)((v & 1) ? (old >> 16) : (old & 0xffffu));
            }
        }
    } else {
        for (int e = s * slice_len + (int)threadIdx.x; e < e1; e += 256) {
            unsigned v = (unsigned)(arr[e] - c0);
            if (v < (unsigned)lim)
                atomicAdd(&hp[v >> 1], (v & 1) ? 0x10000u : 1u);
        }
    }
    __syncthreads();
    u16* outp = (role ? phi : pho) + (size_t)s * N + c0;
    for (int i = threadIdx.x; i < lim; i += 256) {
        unsigned w = hp[i >> 1];
        outp[i] = (u16)((i & 1) ? (w >> 16) : (w & 0xffffu));
    }
}

// ---------------------------------------------------------------- merge partials -> norms; phi -> slice-exclusive prefix
__global__ void merge_norm_kernel(const u16* __restrict__ pho, u16* __restrict__ phi,
                                  float* __restrict__ norm_src, float* __restrict__ norm_dst,
                                  int* __restrict__ deg_in_total, int N) {
    int n = blockIdx.x * 256 + threadIdx.x;
    if (n >= N) return;
    int so = 0;
    #pragma unroll 8
    for (int s = 0; s < NSLICE; ++s) so += pho[(size_t)s * N + n];
    norm_src[n] = rsqrtf(fmaxf((float)so, 1.0f));
    int run = 0;
    #pragma unroll 8
    for (int s = 0; s < NSLICE; ++s) {
        int v = phi[(size_t)s * N + n];
        phi[(size_t)s * N + n] = (u16)run;   // exclusive prefix over slices within node bucket
        run += v;
    }
    deg_in_total[n] = run;
    norm_dst[n] = rsqrtf(fmaxf((float)run, 1.0f));
}

// ---------------------------------------------------------------- prescale: Xn = f16(feat * norm_src[row])
__global__ void prescale_kernel(const float* __restrict__ feat, const float* __restrict__ ns,
                                f16x4* __restrict__ out, int count /* N*32 */) {
    int i = blockIdx.x * 256 + threadIdx.x;
    if (i >= count) return;
    float4 v = ((const float4*)feat)[i];
    float s = ns[i >> 5];
    f16x4 o = { (f16)(v.x * s), (f16)(v.y * s), (f16)(v.z * s), (f16)(v.w * s) };
    out[i] = o;
}

// ---------------------------------------------------------------- hierarchical scan
__global__ __launch_bounds__(256) void scan1_kernel(const int* __restrict__ deg,
                                                    int* __restrict__ partial,
                                                    int* __restrict__ blocksums, int n) {
    __shared__ int wsum[4];
    int lane = threadIdx.x & 63, wid = threadIdx.x >> 6;
    int base = blockIdx.x * SCAN_CHUNK + (int)threadIdx.x * 8;
    int v[8]; int tsum = 0;
    #pragma unroll
    for (int i = 0; i < 8; ++i) { v[i] = (base + i < n) ? deg[base + i] : 0; tsum += v[i]; }
    int s = tsum;
    #pragma unroll
    for (int off = 1; off < 64; off <<= 1) {
        int t = __shfl_up(s, off);
        if (lane >= off) s += t;
    }
    if (lane == 63) wsum[wid] = s;
    __syncthreads();
    int woff = 0;
    for (int w = 0; w < wid; ++w) woff += wsum[w];
    int run = woff + s - tsum;
    #pragma unroll
    for (int i = 0; i < 8; ++i) {
        if (base + i < n) partial[base + i] = run;
        run += v[i];
    }
    if (threadIdx.x == 255) blocksums[blockIdx.x] = woff + s;
}

__global__ void scan2_kernel(int* __restrict__ bs, int* __restrict__ total_out, int nb) {
    int lane = threadIdx.x;  // 64 threads, 1 wave
    int carry = 0;
    for (int base = 0; base < nb; base += 64) {
        int i = base + lane;
        int v = (i < nb) ? bs[i] : 0;
        int s = v;
        #pragma unroll
        for (int off = 1; off < 64; off <<= 1) {
            int t = __shfl_up(s, off);
            if (lane >= off) s += t;
        }
        if (i < nb) bs[i] = carry + s - v;
        carry += __shfl(s, 63);
    }
    if (lane == 0) *total_out = carry;
}

__global__ void scan3_kernel(int* __restrict__ offsets, const int* __restrict__ bs, int n) {
    int i = blockIdx.x * 256 + threadIdx.x;
    if (i >= n) return;
    offsets[i] += bs[i >> 11];   // SCAN_CHUNK = 2048
}

// ---------------------------------------------------------------- CSR fill: streaming, rank-based, no LDS, no atomics
// grid = (bps, NSLICE): y = slice
__global__ __launch_bounds__(256) void fill_kernel(const int* __restrict__ src, const int* __restrict__ dst,
                                                   const int* __restrict__ offsets, const u16* __restrict__ phi,
                                                   const u16* __restrict__ rank,
                                                   int* __restrict__ csr_src,
                                                   int E, int N, int slice_len) {
    int s = blockIdx.y;
    int e = s * slice_len + blockIdx.x * 256 + threadIdx.x;
    int e1 = min(E, (s + 1) * slice_len);
    if (e >= e1) return;
    int d = dst[e];
    int p = offsets[d] + (int)phi[(size_t)s * N + d] + (int)rank[e];
    csr_src[p] = src[e];
}

// ---------------------------------------------------------------- gather: A[n] = f16(norm_dst[n] * sum_{s in in(n)} x[s])
// x pre-scaled by norm_src. 1 wave per node; 4 lane-groups of 16 x 16B -> 4 src rows per VMEM instr.
__global__ __launch_bounds__(256) void gather_kernel(const f16* __restrict__ x,
                                                     const float* __restrict__ norm_dst,
                                                     const int* __restrict__ offsets,
                                                     const int* __restrict__ csr_src,
                                                     f16* __restrict__ A, int N) {
    int node = __builtin_amdgcn_readfirstlane(blockIdx.x * 4 + ((int)threadIdx.x >> 6));
    int lane = threadIdx.x & 63;
    int g = lane >> 4;          // group 0..3: which edge of the 4-batch
    int l = lane & 15;          // 16 lanes x f16x8 = one 256B row
    if (node >= N) return;
    int beg = offsets[node], end = offsets[node + 1];
    float acc0[8] = {0.f}, acc1[8] = {0.f};
    int e = beg;
    for (; e + 8 <= end; e += 8) {
        int sa = csr_src[e + g];
        int sb = csr_src[e + 4 + g];
        f16x8 ra = *(const f16x8*)(x + (size_t)sa * D + l * 8);
        f16x8 rb = *(const f16x8*)(x + (size_t)sb * D + l * 8);
        #pragma unroll
        for (int j = 0; j < 8; ++j) { acc0[j] += (float)ra[j]; acc1[j] += (float)rb[j]; }
    }
    if (e + 4 <= end) {
        int sa = csr_src[e + g];
        f16x8 ra = *(const f16x8*)(x + (size_t)sa * D + l * 8);
        #pragma unroll
        for (int j = 0; j < 8; ++j) acc0[j] += (float)ra[j];
        e += 4;
    }
    int rem = end - e;          // 0..3
    if (g < rem) {
        int sa = csr_src[e + g];
        f16x8 ra = *(const f16x8*)(x + (size_t)sa * D + l * 8);
        #pragma unroll
        for (int j = 0; j < 8; ++j) acc1[j] += (float)ra[j];
    }
    float nd = norm_dst[node];
    f16x8 o;
    #pragma unroll
    for (int j = 0; j < 8; ++j) {
        float v = acc0[j] + acc1[j];
        v += __shfl_xor(v, 16);
        v += __shfl_xor(v, 32);
        o[j] = (f16)(v * nd);
    }
    if (g == 0) *(f16x8*)(A + (size_t)node * D + l * 8) = o;
}

// ---------------------------------------------------------------- GEMM: out = relu(A[M,128] @ W[128,128] + b) [* rowscale] [+ gate]
template <typename OutT, bool SCALE, bool GATE>
__global__ __launch_bounds__(256) void gemm_kernel(const f16* __restrict__ A,
                                                   const float* __restrict__ Wg,
                                                   const float* __restrict__ bias,
                                                   const float* __restrict__ rowscale,
                                                   const float* __restrict__ wgv,
                                                   const float* __restrict__ bgv,
                                                   float* __restrict__ gate_out,
                                                   OutT* __restrict__ out, int M) {
    __shared__ f16 Wf[4 * 8 * 64 * 8];   // 32 KiB
    for (int i = threadIdx.x; i < 2048; i += 256) {   // i = kg*128 + j
        int kg = i >> 7, j = i & 127;
        int k0 = kg * 8;
        f16x8 tmp;
        #pragma unroll
        for (int b = 0; b < 8; ++b) tmp[b] = (f16)Wg[(k0 + b) * D + j];
        int t = k0 >> 5, c = j >> 4;
        int l = ((k0 & 31) >> 3) * 16 + (j & 15);
        *(f16x8*)&Wf[((t * 8 + c) * 64 + l) * 8] = tmp;
    }
    __syncthreads();
    int wave = threadIdx.x >> 6, lane = threadIdx.x & 63;

    for (int row0 = (blockIdx.x * 4 + wave) * 16; row0 < M; row0 += gridDim.x * 64) {
        int arow = row0 + (lane & 15);
        const f16* Abase = A + arow * D + (lane >> 4) * 8;
        f16x8 a[4];
        #pragma unroll
        for (int t = 0; t < 4; ++t) a[t] = *(const f16x8*)(Abase + t * 32);

        float ns[4];
        if (SCALE) {
            #pragma unroll
            for (int r = 0; r < 4; ++r) ns[r] = rowscale[row0 + (lane >> 4) * 4 + r];
        }
        float dotr[4] = {0.f, 0.f, 0.f, 0.f};

        #pragma unroll
        for (int c = 0; c < 8; ++c) {
            f32x4 acc = {0.f, 0.f, 0.f, 0.f};
            #pragma unroll
            for (int t = 0; t < 4; ++t) {
                f16x8 bf = *(const f16x8*)&Wf[((t * 8 + c) * 64 + lane) * 8];
                acc = __builtin_amdgcn_mfma_f32_16x16x32_f16(a[t], bf, acc, 0, 0, 0);
            }
            int col = c * 16 + (lane & 15);
            float bj = bias[col];
            float wgc = GATE ? wgv[col] : 0.f;
            #pragma unroll
            for (int r = 0; r < 4; ++r) {
                int row = row0 + (lane >> 4) * 4 + r;
                float v = fmaxf(acc[r] + bj, 0.f);
                if (SCALE) v *= ns[r];
                out[row * D + col] = (OutT)v;
                if (GATE) dotr[r] += v * wgc;
            }
        }
        if (GATE) {
            float bg0 = bgv[0];
            #pragma unroll
            for (int r = 0; r < 4; ++r) {
                float d = dotr[r];
                d += __shfl_xor(d, 1); d += __shfl_xor(d, 2);
                d += __shfl_xor(d, 4); d += __shfl_xor(d, 8);
                if ((lane & 15) == 0)
                    gate_out[row0 + (lane >> 4) * 4 + r] = 1.0f / (1.0f + __expf(-(d + bg0)));
            }
        }
    }
}

// ---------------------------------------------------------------- graph ranges (graph_ids sorted)
__global__ void gstart_kernel(const int* __restrict__ gid, int* __restrict__ gstart, int N, int G) {
    int n = blockIdx.x * 256 + threadIdx.x;
    if (n >= N) return;
    int g = gid[n];
    if (n == 0) {
        for (int x = 0; x <= g; ++x) gstart[x] = 0;
    } else {
        int pg = gid[n - 1];
        for (int x = pg + 1; x <= g; ++x) gstart[x] = n;
    }
    if (n == N - 1) {
        for (int x = g + 1; x <= G; ++x) gstart[x] = N;
    }
}

// ---------------------------------------------------------------- wh[g] = sum_{n in graph g} gate[n]*h[n]
__global__ __launch_bounds__(256) void gagg_kernel(const float* __restrict__ h,
                                                   const float* __restrict__ gate,
                                                   const int* __restrict__ gstart,
                                                   float* __restrict__ wh) {
    __shared__ float part[4][D];
    int g = blockIdx.x;
    int wave = threadIdx.x >> 6, lane = threadIdx.x & 63;
    int beg = gstart[g], end = gstart[g + 1];
    float2 acc = {0.f, 0.f};
    for (int n = beg + wave; n < end; n += 4) {
        float gv = gate[n];
        float2 hv = ((const float2*)(h + n * D))[lane];
        acc.x += gv * hv.x;
        acc.y += gv * hv.y;
    }
    part[wave][lane * 2]     = acc.x;
    part[wave][lane * 2 + 1] = acc.y;
    __syncthreads();
    if (wave == 0) {
        float sx = 0.f, sy = 0.f;
        #pragma unroll
        for (int w = 0; w < 4; ++w) { sx += part[w][lane * 2]; sy += part[w][lane * 2 + 1]; }
        float2 o = {sx, sy};
        ((float2*)(wh + g * D))[lane] = o;
    }
}

// ---------------------------------------------------------------- launch
extern "C" void kernel_launch(void* const* d_in, const int* in_sizes, int n_in,
                              void* d_out, int out_size, void* d_ws, size_t ws_size,
                              hipStream_t stream) {
    const int*   src  = (const int*)d_in[0];
    const int*   dst  = (const int*)d_in[1];
    const int*   gid  = (const int*)d_in[2];
    const float* feat = (const float*)d_in[3];
    const float* w1   = (const float*)d_in[4];
    const float* b1   = (const float*)d_in[5];
    const float* w2   = (const float*)d_in[6];
    const float* b2   = (const float*)d_in[7];
    const float* wg   = (const float*)d_in[8];
    const float* bg   = (const float*)d_in[9];
    int E = in_sizes[0];
    int N = in_sizes[2];
    const int G = G_GRAPHS;

    int binsz     = (N + CCHUNK - 1) / CCHUNK;     // 12500 for N=100000 (must be <= BINMAX)
    int slice_len = (E + NSLICE - 1) / NSLICE;     // 12500 for E=800000
    int bps       = (slice_len + 255) / 256;       // fill blocks per slice

    char* ws = (char*)d_ws;
    size_t off = 0;
    auto carve = [&](size_t bytes) { void* p = ws + off; off = (off + bytes + 255) & ~(size_t)255; return p; };
    u16*   pho       = (u16*)  carve((size_t)NSLICE * N * 2);
    u16*   phi       = (u16*)  carve((size_t)NSLICE * N * 2);   // becomes slice-exclusive prefix
    u16*   rank      = (u16*)  carve((size_t)E * 2);
    float* norm_src  = (float*)carve((size_t)N * 4);
    float* norm_dst  = (float*)carve((size_t)N * 4);
    int*   deg_in_t  = (int*)  carve((size_t)N * 4);
    int*   offsets   = (int*)  carve((size_t)(N + 1) * 4);
    int*   blocksums = (int*)  carve((size_t)64 * 4);
    int*   csr_src   = (int*)  carve((size_t)E * 4);
    f16*   Xh        = (f16*)  carve((size_t)N * D * 2);  // Xn for layer1, then h1*norm_src
    f16*   A         = (f16*)  carve((size_t)N * D * 2);
    float* gate      = (float*)carve((size_t)N * 4);
    int*   gstart    = (int*)  carve((size_t)(G + 1) * 4);

    float* wh_out = (float*)d_out;                  // [512, 128]
    float* h_out  = (float*)d_out + (size_t)G * D;  // [N, 128]

    int nb = (N + SCAN_CHUNK - 1) / SCAN_CHUNK;     // 49 blocks for N=100000

    dim3 hgrid(CCHUNK, 2, NSLICE);
    hist_kernel<<<hgrid, 256, 0, stream>>>(src, dst, pho, phi, rank, E, N, slice_len, binsz);
    merge_norm_kernel<<<(N + 255) / 256, 256, 0, stream>>>(pho, phi, norm_src, norm_dst, deg_in_t, N);
    prescale_kernel<<<(N * 32 + 255) / 256, 256, 0, stream>>>(feat, norm_src, (f16x4*)Xh, N * 32);

    scan1_kernel<<<nb, 256, 0, stream>>>(deg_in_t, offsets, blocksums, N);
    scan2_kernel<<<1, 64, 0, stream>>>(blocksums, offsets + N, nb);
    scan3_kernel<<<(N + 255) / 256, 256, 0, stream>>>(offsets, blocksums, N);
    dim3 fgrid(bps, NSLICE);
    fill_kernel<<<fgrid, 256, 0, stream>>>(src, dst, offsets, phi, rank, csr_src, E, N, slice_len);

    // layer 1
    gather_kernel<<<(N + 3) / 4, 256, 0, stream>>>(Xh, norm_dst, offsets, csr_src, A, N);
    gemm_kernel<f16, true, false><<<512, 256, 0, stream>>>(A, w1, b1, norm_src, nullptr, nullptr, nullptr, Xh, N);
    // layer 2
    gather_kernel<<<(N + 3) / 4, 256, 0, stream>>>(Xh, norm_dst, offsets, csr_src, A, N);
    gemm_kernel<float, false, true><<<512, 256, 0, stream>>>(A, w2, b2, nullptr, wg, bg, gate, h_out, N);

    gstart_kernel<<<(N + 255) / 256, 256, 0, stream>>>(gid, gstart, N, G);
    gagg_kernel<<<G, 256, 0, stream>>>(h_out, gate, gstart, wh_out);
}